// Round 15
// baseline (22.997 us; speedup 1.0000x reference)
//
#include <hip/hip_runtime.h>
#include <hip/hip_bf16.h>

// Decorrelation, single fused kernel, register-only tiny-GEMM per 16-sample tile.
//   out[n,j] = sum_k A[n,k]*B[k,j],  K=160
//   A[n, k(i,kk)] = u_i^kk * (1-u_i)^(9-kk) * x[n,i]        (NO binomial)
//   B[k(i,kk), j] = i<j  ? binom(9,kk)*params[kk, pair(i,j)]
//                 : i==j ? binom(9,kk)   (sum_kk BIN u^kk v^(9-kk) = 1 -> +x_j)
//                 : 0
// k-axis relabeled so lane (m15,g)'s A-fragment is built from its OWN float4
// (verified R5..R13). Operand-swapped MFMA (R11): lane holds
// out[base+m15, 4g..4g+3] -> one global_store_dwordx4 (NT) per tile.
// Barrier reorder (R13): params->LDS + barrier BEFORE x-loads.
//
// vs R13 (18.2us, best): TPW back to 8 (R14's TPW=4 regressed: halved MLP
// without raising occupancy) + __launch_bounds__(256, 5): cap VGPR ~102 to
// force 5 waves/SIMD (was ~4 at VGPR~110-130). Isolates occupancy as the
// variable while keeping 8KB/wave in flight.

#define DVARS 16
#define KB 10
#define STEPS 5          // K=160 / 32
#define WPB 4            // waves per block (256 threads)
#define TPW 8            // tiles per wave

typedef _Float16 f16x8 __attribute__((ext_vector_type(8)));
typedef __fp16   h16x2 __attribute__((ext_vector_type(2)));
typedef float    f32x4 __attribute__((ext_vector_type(4)));
typedef float    v2f   __attribute__((ext_vector_type(2)));

static __device__ __forceinline__ unsigned packh2(float a, float b) {
    h16x2 h = __builtin_amdgcn_cvt_pkrtz(a, b);   // a -> low, b -> high
    unsigned r;
    __builtin_memcpy(&r, &h, 4);
    return r;
}

__global__ __launch_bounds__(256, 5) void decorr_fused(
        const float* __restrict__ x,
        const float* __restrict__ params,
        const float* __restrict__ prange,
        float* __restrict__ out,
        int nSamples, int nTiles)
{
    __shared__ float  Ps[KB * 120];      // 4.8 KB params table
    __shared__ float2 LIs[DVARS];

    int tid  = threadIdx.x;
    int lane = tid & 63;
    int wid  = tid >> 6;
    int g    = lane >> 4;
    int m15  = lane & 15;

    int t0 = (blockIdx.x * WPB + wid) * TPW;

    // ---- stage params into LDS FIRST, then barrier (x-loads come after, so
    //      the barrier's vmcnt(0) drain never touches them)
    for (int idx = tid; idx < KB * 120; idx += 256) Ps[idx] = params[idx];
    if (tid < DVARS) {
        float lo = prange[tid];
        LIs[tid] = make_float2(lo, 1.0f / (prange[DVARS + tid] - lo));
    }
    __syncthreads();

    // ---- issue ALL x-tile loads now: 8KB in flight, overlapping B-build
    float4 xv[TPW];
#pragma unroll
    for (int t = 0; t < TPW; ++t) {
        int row = (t0 + t) * 16 + m15;
        if (row > nSamples - 1) row = nSamples - 1;   // tail clamp (loads only)
        xv[t] = *reinterpret_cast<const float4*>(x + (size_t)row * DVARS + 4 * g);
    }

    // ---- B fragments from LDS gathers (once per wave, amortized 8 tiles)
    const float BIN[KB] = {1.f, 9.f, 36.f, 84.f, 126.f, 126.f, 84.f, 36.f, 9.f, 1.f};
    int n = m15;                        // this lane's output column j
    int tri = n * (n - 1) / 2;
    f16x8 bfr[STEPS];
#pragma unroll
    for (int s = 0; s < STEPS; ++s) {
        unsigned d[4];
#pragma unroll
        for (int h = 0; h < 4; ++h) {
            float w01[2];
#pragma unroll
            for (int e2 = 0; e2 < 2; ++e2) {
                int c  = 8 * s + 2 * h + e2;     // lane-local flat index 0..39
                int i  = 4 * g + c / 10;
                int kk = c % 10;
                int idx = kk * 120 + tri + ((i < n) ? i : 0);   // clamped: in-bounds
                float p = Ps[idx];
                w01[e2] = (i < n) ? BIN[kk] * p : ((i == n) ? BIN[kk] : 0.f);
            }
            d[h] = packh2(w01[0], w01[1]);
        }
        __builtin_memcpy(&bfr[s], d, 16);
    }

    // ---- normalization constants, packed for the v2f basis chain
    v2f lo2[2], inv2[2];
#pragma unroll
    for (int p = 0; p < 2; ++p) {
        float2 a = LIs[4 * g + 2 * p];
        float2 b = LIs[4 * g + 2 * p + 1];
        lo2[p]  = (v2f){a.x, b.x};
        inv2[p] = (v2f){a.y, b.y};
    }

    // ---- per tile: packed basis build, 5 operand-swapped MFMAs, NT float4 store
#pragma unroll
    for (int t = 0; t < TPW; ++t) {
        unsigned afr[STEPS * 4];                  // 20 dwords = 40 halves
        const float* xl = reinterpret_cast<const float*>(&xv[t]);
#pragma unroll
        for (int p = 0; p < 2; ++p) {             // covariate pair q = (2p, 2p+1)
            v2f xm = (v2f){xl[2 * p], xl[2 * p + 1]};
            v2f u = (xm - lo2[p]) * inv2[p];
            v2f v = (v2f){1.f, 1.f} - u;
            v2f vx[KB];
            vx[0] = xm;                            // vx[k] = v^k * x_i
#pragma unroll
            for (int k = 1; k < KB; ++k) vx[k] = vx[k - 1] * v;
            v2f tk[KB];
            tk[0] = vx[KB - 1];
            v2f run = u;
#pragma unroll
            for (int k = 1; k < KB; ++k) {         // tk[k] = u^k v^(9-k) x_i
                tk[k] = run * vx[KB - 1 - k];
                if (k < KB - 1) run = run * u;
            }
#pragma unroll
            for (int h = 0; h < 5; ++h) {          // afr[5q+h] = halves (10q+2h, +1)
                afr[5 * (2 * p)     + h] = packh2(tk[2 * h].x, tk[2 * h + 1].x);
                afr[5 * (2 * p + 1) + h] = packh2(tk[2 * h].y, tk[2 * h + 1].y);
            }
        }

        f32x4 acc = {0.f, 0.f, 0.f, 0.f};
#pragma unroll
        for (int s = 0; s < STEPS; ++s) {
            f16x8 a;
            __builtin_memcpy(&a, &afr[4 * s], 16);
            // swapped operands: D^T -> lane holds out[base+m15, 4g..4g+3]
            acc = __builtin_amdgcn_mfma_f32_16x16x32_f16(bfr[s], a, acc, 0, 0, 0);
        }

        int sample = (t0 + t) * 16 + m15;
        if (sample < nSamples) {
            __builtin_nontemporal_store(
                acc, reinterpret_cast<f32x4*>(out + (size_t)sample * DVARS + 4 * g));
        }
    }
}

extern "C" void kernel_launch(void* const* d_in, const int* in_sizes, int n_in,
                              void* d_out, int out_size, void* d_ws, size_t ws_size,
                              hipStream_t stream) {
    const float* x      = (const float*)d_in[0];   // [N, 16]
    const float* params = (const float*)d_in[1];   // [10, 120]
    const float* prange = (const float*)d_in[2];   // [2, 16]
    float* out = (float*)d_out;

    int nSamples = in_sizes[0] / DVARS;
    int nTiles = (nSamples + 15) / 16;

    int tilesPerBlock = WPB * TPW;                 // 32
    int blocks = (nTiles + tilesPerBlock - 1) / tilesPerBlock;

    decorr_fused<<<blocks, 256, 0, stream>>>(x, params, prange, out,
                                             nSamples, nTiles);
}

// Round 16
// 17.710 us; speedup vs baseline: 1.2985x; 1.2985x over previous
//
#include <hip/hip_runtime.h>
#include <hip/hip_bf16.h>

// Decorrelation, single fused kernel, register-only tiny-GEMM per 16-sample tile.
//   out[n,j] = sum_k A[n,k]*B[k,j],  K=160
//   A[n, k(i,kk)] = u_i^kk * (1-u_i)^(9-kk) * x[n,i]        (NO binomial)
//   B[k(i,kk), j] = i<j  ? binom(9,kk)*params[kk, pair(i,j)]
//                 : i==j ? binom(9,kk)   (sum_kk BIN u^kk v^(9-kk) = 1 -> +x_j)
//                 : 0
// k-axis relabeled so lane (m15,g)'s A-fragment is built from its OWN float4
// (verified R5..R13). Operand-swapped MFMA (R11): lane holds
// out[base+m15, 4g..4g+3] -> one global_store_dwordx4 (NT) per tile.
//
// vs R13 (18.2us, best): RAW BARRIER + vmcnt-ordered loads. R13's
// __syncthreads serialized {params load -> LDS -> barrier} BEFORE x-loads
// could even issue (~2us of head latency per block generation). Now:
// issue params loads FIRST (oldest in vmcnt queue), then prange, then all
// 8 x-loads; ds_write waits counted vmcnt(10) (x-loads stay in flight);
// then lgkmcnt(0) + raw s_barrier (no vmcnt drain, HK technique) + compiler
// fence. x-loads issue at wave start and drain under compute.
// R14/R15 lesson: do NOT touch TPW or launch_bounds (both regressed).

#define DVARS 16
#define KB 10
#define STEPS 5          // K=160 / 32
#define WPB 4            // waves per block (256 threads)
#define TPW 8            // tiles per wave

typedef _Float16 f16x8 __attribute__((ext_vector_type(8)));
typedef __fp16   h16x2 __attribute__((ext_vector_type(2)));
typedef float    f32x4 __attribute__((ext_vector_type(4)));
typedef float    v2f   __attribute__((ext_vector_type(2)));

static __device__ __forceinline__ unsigned packh2(float a, float b) {
    h16x2 h = __builtin_amdgcn_cvt_pkrtz(a, b);   // a -> low, b -> high
    unsigned r;
    __builtin_memcpy(&r, &h, 4);
    return r;
}

__global__ __launch_bounds__(256) void decorr_fused(
        const float* __restrict__ x,
        const float* __restrict__ params,
        const float* __restrict__ prange,
        float* __restrict__ out,
        int nSamples, int nTiles)
{
    __shared__ float Ps[KB * 120];       // 4.8 KB params table

    int tid  = threadIdx.x;
    int lane = tid & 63;
    int wid  = tid >> 6;
    int g    = lane >> 4;
    int m15  = lane & 15;

    int t0 = (blockIdx.x * WPB + wid) * TPW;

    // ---- 1. params global loads FIRST (oldest in the vmcnt queue)
    float pstage[5];
#pragma unroll
    for (int r = 0; r < 5; ++r) {
        int idx = tid + 256 * r;
        pstage[r] = params[idx < KB * 120 ? idx : KB * 120 - 1];  // uniform load, clamped
    }

    // ---- 2. prange per-lane (2x dwordx4, L2-hot; before x so its consumer
    //         waits vmcnt(8), not vmcnt(0))
    float4 lo4 = *reinterpret_cast<const float4*>(prange + 4 * g);
    float4 hi4 = *reinterpret_cast<const float4*>(prange + DVARS + 4 * g);

    // ---- 3. ALL x-tile loads (newest; stay in flight across the barrier)
    float4 xv[TPW];
#pragma unroll
    for (int t = 0; t < TPW; ++t) {
        int row = (t0 + t) * 16 + m15;
        if (row > nSamples - 1) row = nSamples - 1;   // tail clamp (loads only)
        xv[t] = *reinterpret_cast<const float4*>(x + (size_t)row * DVARS + 4 * g);
    }

    // ---- 4. stage params into LDS (compiler waits counted vmcnt for pstage)
#pragma unroll
    for (int r = 0; r < 5; ++r) {
        int idx = tid + 256 * r;
        if (idx < KB * 120) Ps[idx] = pstage[r];
    }

    // ---- 5. raw barrier: lgkmcnt(0) only -- NO vmcnt(0) drain
    asm volatile("s_waitcnt lgkmcnt(0)" ::: "memory");
    __builtin_amdgcn_s_barrier();
    asm volatile("" ::: "memory");      // compiler fence: keep Ps reads below

    // ---- 6. B fragments from LDS gathers (once per wave, amortized 8 tiles)
    const float BIN[KB] = {1.f, 9.f, 36.f, 84.f, 126.f, 126.f, 84.f, 36.f, 9.f, 1.f};
    int n = m15;                        // this lane's output column j
    int tri = n * (n - 1) / 2;
    f16x8 bfr[STEPS];
#pragma unroll
    for (int s = 0; s < STEPS; ++s) {
        unsigned d[4];
#pragma unroll
        for (int h = 0; h < 4; ++h) {
            float w01[2];
#pragma unroll
            for (int e2 = 0; e2 < 2; ++e2) {
                int c  = 8 * s + 2 * h + e2;     // lane-local flat index 0..39
                int i  = 4 * g + c / 10;
                int kk = c % 10;
                int idx = kk * 120 + tri + ((i < n) ? i : 0);   // clamped: in-bounds
                float p = Ps[idx];
                w01[e2] = (i < n) ? BIN[kk] * p : ((i == n) ? BIN[kk] : 0.f);
            }
            d[h] = packh2(w01[0], w01[1]);
        }
        __builtin_memcpy(&bfr[s], d, 16);
    }

    // ---- 7. normalization constants, packed for the v2f basis chain
    const float* lol = reinterpret_cast<const float*>(&lo4);
    const float* hil = reinterpret_cast<const float*>(&hi4);
    v2f lo2[2], inv2[2];
#pragma unroll
    for (int p = 0; p < 2; ++p) {
        lo2[p]  = (v2f){lol[2 * p], lol[2 * p + 1]};
        inv2[p] = (v2f){1.0f / (hil[2 * p] - lol[2 * p]),
                        1.0f / (hil[2 * p + 1] - lol[2 * p + 1])};
    }

    // ---- 8. per tile: packed basis build, 5 operand-swapped MFMAs, NT store
#pragma unroll
    for (int t = 0; t < TPW; ++t) {
        unsigned afr[STEPS * 4];                  // 20 dwords = 40 halves
        const float* xl = reinterpret_cast<const float*>(&xv[t]);
#pragma unroll
        for (int p = 0; p < 2; ++p) {             // covariate pair q = (2p, 2p+1)
            v2f xm = (v2f){xl[2 * p], xl[2 * p + 1]};
            v2f u = (xm - lo2[p]) * inv2[p];
            v2f v = (v2f){1.f, 1.f} - u;
            v2f vx[KB];
            vx[0] = xm;                            // vx[k] = v^k * x_i
#pragma unroll
            for (int k = 1; k < KB; ++k) vx[k] = vx[k - 1] * v;
            v2f tk[KB];
            tk[0] = vx[KB - 1];
            v2f run = u;
#pragma unroll
            for (int k = 1; k < KB; ++k) {         // tk[k] = u^k v^(9-k) x_i
                tk[k] = run * vx[KB - 1 - k];
                if (k < KB - 1) run = run * u;
            }
#pragma unroll
            for (int h = 0; h < 5; ++h) {          // afr[5q+h] = halves (10q+2h, +1)
                afr[5 * (2 * p)     + h] = packh2(tk[2 * h].x, tk[2 * h + 1].x);
                afr[5 * (2 * p + 1) + h] = packh2(tk[2 * h].y, tk[2 * h + 1].y);
            }
        }

        f32x4 acc = {0.f, 0.f, 0.f, 0.f};
#pragma unroll
        for (int s = 0; s < STEPS; ++s) {
            f16x8 a;
            __builtin_memcpy(&a, &afr[4 * s], 16);
            // swapped operands: D^T -> lane holds out[base+m15, 4g..4g+3]
            acc = __builtin_amdgcn_mfma_f32_16x16x32_f16(bfr[s], a, acc, 0, 0, 0);
        }

        int sample = (t0 + t) * 16 + m15;
        if (sample < nSamples) {
            __builtin_nontemporal_store(
                acc, reinterpret_cast<f32x4*>(out + (size_t)sample * DVARS + 4 * g));
        }
    }
}

extern "C" void kernel_launch(void* const* d_in, const int* in_sizes, int n_in,
                              void* d_out, int out_size, void* d_ws, size_t ws_size,
                              hipStream_t stream) {
    const float* x      = (const float*)d_in[0];   // [N, 16]
    const float* params = (const float*)d_in[1];   // [10, 120]
    const float* prange = (const float*)d_in[2];   // [2, 16]
    float* out = (float*)d_out;

    int nSamples = in_sizes[0] / DVARS;
    int nTiles = (nSamples + 15) / 16;

    int tilesPerBlock = WPB * TPW;                 // 32
    int blocks = (nTiles + tilesPerBlock - 1) / tilesPerBlock;

    decorr_fused<<<blocks, 256, 0, stream>>>(x, params, prange, out,
                                             nSamples, nTiles);
}

// Round 17
// 17.273 us; speedup vs baseline: 1.3314x; 1.0253x over previous
//
#include <hip/hip_runtime.h>
#include <hip/hip_bf16.h>

// Decorrelation, single fused kernel, register-only tiny-GEMM per 16-sample tile.
//   out[n,j] = sum_k A[n,k]*B[k,j],  K=160
//   A[n, k(i,kk)] = u_i^kk * (1-u_i)^(9-kk) * x[n,i]        (NO binomial)
//   B[k(i,kk), j] = i<j  ? binom(9,kk)*params[kk, pair(i,j)]
//                 : i==j ? binom(9,kk)   (diagonal -> +x_j)
//                 : 0
// k-axis relabeled so lane (m15,g)'s A-fragment is built from its OWN float4
// (verified R5..R16). Operand-swapped MFMA (R11): lane holds
// out[base+m15, 4g..4g+3] -> one global_store_dwordx4 (NT) per tile.
// vmcnt-ordered loads + raw s_barrier (R16): params oldest, then prange,
// then 8 x-loads; lgkmcnt(0)-only barrier keeps x in flight.
//
// vs R16 (17.7us): (1) __launch_bounds__(256,4) -- cap VGPR at 128 to
// guarantee 4 waves/SIMD single-generation residency (R15's 5-wave cap at
// ~102 spilled; 128 is at natural usage). (2) FULL/guarded path split:
// N=500000 is an exact multiple of 16, so 3905/3907 waves run with zero
// load clamps / store guards (wave-uniform branch).

#define DVARS 16
#define KB 10
#define STEPS 5          // K=160 / 32
#define WPB 4            // waves per block (256 threads)
#define TPW 8            // tiles per wave

typedef _Float16 f16x8 __attribute__((ext_vector_type(8)));
typedef __fp16   h16x2 __attribute__((ext_vector_type(2)));
typedef float    f32x4 __attribute__((ext_vector_type(4)));
typedef float    v2f   __attribute__((ext_vector_type(2)));

static __device__ __forceinline__ unsigned packh2(float a, float b) {
    h16x2 h = __builtin_amdgcn_cvt_pkrtz(a, b);   // a -> low, b -> high
    unsigned r;
    __builtin_memcpy(&r, &h, 4);
    return r;
}

template <bool FULL>
static __device__ __forceinline__ void wave_body(
        const float* __restrict__ x,
        const float* __restrict__ prange,
        float* __restrict__ out,
        const float* __restrict__ Ps,   // LDS params (already synced)
        int t0, int g, int m15, int nSamples, int nTiles)
{
    // ---- x-tile loads (params/prange already in the vmcnt queue before us)
    float4 xv[TPW];
#pragma unroll
    for (int t = 0; t < TPW; ++t) {
        int row = (t0 + t) * 16 + m15;
        if (!FULL) { if (row > nSamples - 1) row = nSamples - 1; }
        xv[t] = *reinterpret_cast<const float4*>(x + (size_t)row * DVARS + 4 * g);
    }

    // ---- B fragments from LDS gathers (once per wave, amortized 8 tiles)
    const float BIN[KB] = {1.f, 9.f, 36.f, 84.f, 126.f, 126.f, 84.f, 36.f, 9.f, 1.f};
    int n = m15;                        // this lane's output column j
    int tri = n * (n - 1) / 2;
    f16x8 bfr[STEPS];
#pragma unroll
    for (int s = 0; s < STEPS; ++s) {
        unsigned d[4];
#pragma unroll
        for (int h = 0; h < 4; ++h) {
            float w01[2];
#pragma unroll
            for (int e2 = 0; e2 < 2; ++e2) {
                int c  = 8 * s + 2 * h + e2;     // lane-local flat index 0..39
                int i  = 4 * g + c / 10;
                int kk = c % 10;
                int idx = kk * 120 + tri + ((i < n) ? i : 0);   // clamped: in-bounds
                float p = Ps[idx];
                w01[e2] = (i < n) ? BIN[kk] * p : ((i == n) ? BIN[kk] : 0.f);
            }
            d[h] = packh2(w01[0], w01[1]);
        }
        __builtin_memcpy(&bfr[s], d, 16);
    }

    // ---- normalization constants, packed for the v2f basis chain
    float4 lo4 = *reinterpret_cast<const float4*>(prange + 4 * g);
    float4 hi4 = *reinterpret_cast<const float4*>(prange + DVARS + 4 * g);
    const float* lol = reinterpret_cast<const float*>(&lo4);
    const float* hil = reinterpret_cast<const float*>(&hi4);
    v2f lo2[2], inv2[2];
#pragma unroll
    for (int p = 0; p < 2; ++p) {
        lo2[p]  = (v2f){lol[2 * p], lol[2 * p + 1]};
        inv2[p] = (v2f){1.0f / (hil[2 * p] - lol[2 * p]),
                        1.0f / (hil[2 * p + 1] - lol[2 * p + 1])};
    }

    // ---- per tile: packed basis build, 5 operand-swapped MFMAs, NT store
#pragma unroll
    for (int t = 0; t < TPW; ++t) {
        unsigned afr[STEPS * 4];                  // 20 dwords = 40 halves
        const float* xl = reinterpret_cast<const float*>(&xv[t]);
#pragma unroll
        for (int p = 0; p < 2; ++p) {             // covariate pair q = (2p, 2p+1)
            v2f xm = (v2f){xl[2 * p], xl[2 * p + 1]};
            v2f u = (xm - lo2[p]) * inv2[p];
            v2f v = (v2f){1.f, 1.f} - u;
            v2f vx[KB];
            vx[0] = xm;                            // vx[k] = v^k * x_i
#pragma unroll
            for (int k = 1; k < KB; ++k) vx[k] = vx[k - 1] * v;
            v2f tk[KB];
            tk[0] = vx[KB - 1];
            v2f run = u;
#pragma unroll
            for (int k = 1; k < KB; ++k) {         // tk[k] = u^k v^(9-k) x_i
                tk[k] = run * vx[KB - 1 - k];
                if (k < KB - 1) run = run * u;
            }
#pragma unroll
            for (int h = 0; h < 5; ++h) {          // afr[5q+h] = halves (10q+2h, +1)
                afr[5 * (2 * p)     + h] = packh2(tk[2 * h].x, tk[2 * h + 1].x);
                afr[5 * (2 * p + 1) + h] = packh2(tk[2 * h].y, tk[2 * h + 1].y);
            }
        }

        f32x4 acc = {0.f, 0.f, 0.f, 0.f};
#pragma unroll
        for (int s = 0; s < STEPS; ++s) {
            f16x8 a;
            __builtin_memcpy(&a, &afr[4 * s], 16);
            // swapped operands: D^T -> lane holds out[base+m15, 4g..4g+3]
            acc = __builtin_amdgcn_mfma_f32_16x16x32_f16(bfr[s], a, acc, 0, 0, 0);
        }

        int sample = (t0 + t) * 16 + m15;
        if (FULL || sample < nSamples) {
            __builtin_nontemporal_store(
                acc, reinterpret_cast<f32x4*>(out + (size_t)sample * DVARS + 4 * g));
        }
    }
}

__global__ __launch_bounds__(256, 4) void decorr_fused(
        const float* __restrict__ x,
        const float* __restrict__ params,
        const float* __restrict__ prange,
        float* __restrict__ out,
        int nSamples, int nTiles)
{
    __shared__ float Ps[KB * 120];       // 4.8 KB params table

    int tid  = threadIdx.x;
    int lane = tid & 63;
    int wid  = tid >> 6;
    int g    = lane >> 4;
    int m15  = lane & 15;

    int t0 = (blockIdx.x * WPB + wid) * TPW;

    // ---- params global loads FIRST (oldest in the vmcnt queue)
    float pstage[5];
#pragma unroll
    for (int r = 0; r < 5; ++r) {
        int idx = tid + 256 * r;
        pstage[r] = params[idx < KB * 120 ? idx : KB * 120 - 1];
    }

    // ---- stage params into LDS (counted vmcnt wait; later loads unaffected)
#pragma unroll
    for (int r = 0; r < 5; ++r) {
        int idx = tid + 256 * r;
        if (idx < KB * 120) Ps[idx] = pstage[r];
    }

    // ---- raw barrier: lgkmcnt(0) only -- NO vmcnt(0) drain
    asm volatile("s_waitcnt lgkmcnt(0)" ::: "memory");
    __builtin_amdgcn_s_barrier();
    asm volatile("" ::: "memory");      // compiler fence: keep Ps reads below

    if (t0 + TPW <= nTiles && (t0 + TPW) * 16 <= nSamples) {
        wave_body<true>(x, prange, out, Ps, t0, g, m15, nSamples, nTiles);
    } else if (t0 < nTiles) {
        wave_body<false>(x, prange, out, Ps, t0, g, m15, nSamples, nTiles);
    }
}

extern "C" void kernel_launch(void* const* d_in, const int* in_sizes, int n_in,
                              void* d_out, int out_size, void* d_ws, size_t ws_size,
                              hipStream_t stream) {
    const float* x      = (const float*)d_in[0];   // [N, 16]
    const float* params = (const float*)d_in[1];   // [10, 120]
    const float* prange = (const float*)d_in[2];   // [2, 16]
    float* out = (float*)d_out;

    int nSamples = in_sizes[0] / DVARS;
    int nTiles = (nSamples + 15) / 16;

    int tilesPerBlock = WPB * TPW;                 // 32
    int blocks = (nTiles + tilesPerBlock - 1) / tilesPerBlock;

    decorr_fused<<<blocks, 256, 0, stream>>>(x, params, prange, out,
                                             nSamples, nTiles);
}